// Round 1
// baseline (395.910 us; speedup 1.0000x reference)
//
#include <hip/hip_runtime.h>

// Problem constants (from reference setup_inputs)
#define BB 4
#define CC 3
#define TT 103
#define HH 224
#define WW 224
// plane = H*W = 50176 floats = 12544 float4; 12544/256 = 49 blocks per plane
#define VEC4_PER_PLANE (HH * WW / 4)      // 12544
#define BLOCKS_PER_PLANE (VEC4_PER_PLANE / 256)  // 49
#define VEC4_PER_ROW (WW / 4)             // 56

__global__ __launch_bounds__(256) void SBS_44547400794465_kernel(
    const float* __restrict__ video,
    const float* __restrict__ bbox,
    const int* __restrict__ index,
    float* __restrict__ out)
{
    const int plane = blockIdx.x / BLOCKS_PER_PLANE;   // (b,c,t) plane id
    const int chunk = blockIdx.x % BLOCKS_PER_PLANE;
    const int b = plane / (CC * TT);
    const int rem = plane % (CC * TT);
    const int c = rem / TT;
    const int t = rem % TT;
    const int ib = index[b];

    // --- rect for batch b at frame t (clipped rect -> "mask") ---
    const float* bb = bbox + (size_t)(b * TT + t) * 8;
    float xmn = fminf(fminf(bb[0], bb[2]), fminf(bb[4], bb[6]));
    float xmx = fmaxf(fmaxf(bb[0], bb[2]), fmaxf(bb[4], bb[6]));
    float ymn = fminf(fminf(bb[1], bb[3]), fminf(bb[5], bb[7]));
    float ymx = fmaxf(fmaxf(bb[1], bb[3]), fmaxf(bb[5], bb[7]));
    const int cx0 = (int)fmaxf(xmn, 0.0f);
    const int cy0 = (int)fmaxf(ymn, 0.0f);
    const int cx1 = (int)fminf(xmx, (float)WW);
    const int cy1 = (int)fminf(ymx, (float)HH);

    // --- rect for batch ib=index[b] at frame t (unclipped ints -> "m_br[index]") ---
    const float* bi = bbox + (size_t)(ib * TT + t) * 8;
    float xmni = fminf(fminf(bi[0], bi[2]), fminf(bi[4], bi[6]));
    float xmxi = fmaxf(fmaxf(bi[0], bi[2]), fmaxf(bi[4], bi[6]));
    float ymni = fminf(fminf(bi[1], bi[3]), fminf(bi[5], bi[7]));
    float ymxi = fmaxf(fmaxf(bi[1], bi[3]), fmaxf(bi[5], bi[7]));
    const int x0 = (int)xmni;
    const int x1 = (int)xmxi;
    const int y0 = (int)ymni;
    const int y1 = (int)ymxi;

    // --- pixel coordinates for this thread's float4 ---
    const int hw4 = chunk * 256 + (int)threadIdx.x;   // [0, 12544)
    const int h = hw4 / VEC4_PER_ROW;
    const int w = (hw4 % VEC4_PER_ROW) * 4;

    const size_t off  = ((size_t)(b  * CC + c) * TT + t) * (HH * WW) + (size_t)h * WW + w;
    const size_t offi = ((size_t)(ib * CC + c) * TT + t) * (HH * WW) + (size_t)h * WW + w;

    const bool hin = (h >= cy0) & (h <= cy1);
    const bool hbr = (h >= y0) & (h <= y1);

    bool m[4], mb[4];
#pragma unroll
    for (int j = 0; j < 4; ++j) {
        const int wj = w + j;
        m[j]  = hin & (wj >= cx0) & (wj <= cx1);
        mb[j] = hbr & (wj >= x0) & (wj <= x1);
    }

    const bool any_self = m[0] | m[1] | m[2] | m[3];
    const bool any_idx = (!m[0] & !mb[0]) | (!m[1] & !mb[1]) |
                         (!m[2] & !mb[2]) | (!m[3] & !mb[3]);

    float4 vs = make_float4(0.f, 0.f, 0.f, 0.f);
    float4 vi = make_float4(0.f, 0.f, 0.f, 0.f);
    if (any_self) vs = *(const float4*)(video + off);
    if (any_idx)  vi = *(const float4*)(video + offi);

    float4 o;
    o.x = m[0] ? vs.x : (mb[0] ? 0.f : vi.x);
    o.y = m[1] ? vs.y : (mb[1] ? 0.f : vi.y);
    o.z = m[2] ? vs.z : (mb[2] ? 0.f : vi.z);
    o.w = m[3] ? vs.w : (mb[3] ? 0.f : vi.w);

    *(float4*)(out + off) = o;
}

extern "C" void kernel_launch(void* const* d_in, const int* in_sizes, int n_in,
                              void* d_out, int out_size, void* d_ws, size_t ws_size,
                              hipStream_t stream) {
    const float* video = (const float*)d_in[0];
    const float* bbox  = (const float*)d_in[1];
    const int*   index = (const int*)d_in[2];
    float* out = (float*)d_out;

    const int planes = BB * CC * TT;                 // 1236
    const int grid = planes * BLOCKS_PER_PLANE;      // 60564
    SBS_44547400794465_kernel<<<grid, 256, 0, stream>>>(video, bbox, index, out);
}